// Round 9
// baseline (437.143 us; speedup 1.0000x reference)
//
#include <hip/hip_runtime.h>
#include <hip/hip_bf16.h>
#include <cstdint>
#include <cstddef>

#define HDIM 4096
#define MROWS 8192
#define LN_EPS 1e-5f

typedef __bf16 bf16_t;
typedef __bf16 bf16x4_t __attribute__((ext_vector_type(4)));
typedef __bf16 bf16x8_t __attribute__((ext_vector_type(8)));
typedef float f32x4_t __attribute__((ext_vector_type(4)));

typedef const __attribute__((address_space(1))) void gvoid_t;
typedef __attribute__((address_space(3))) void lvoid_t;

__device__ __forceinline__ float softplus_f(float x) {
    return fmaxf(x, 0.f) + log1pf(expf(-fabsf(x)));
}

// ---- W = mu + softplus(rho)*eps  -> bf16 ----
__global__ __launch_bounds__(256) void wgen_kernel(
    const float* __restrict__ mu, const float* __restrict__ rho,
    const float* __restrict__ eps, bf16_t* __restrict__ W)
{
    int i = (blockIdx.x * 256 + threadIdx.x) * 4;
    float4 m = *(const float4*)(mu + i);
    float4 r = *(const float4*)(rho + i);
    float4 e = *(const float4*)(eps + i);
    bf16x4_t o;
    o[0] = (bf16_t)(m.x + softplus_f(r.x) * e.x);
    o[1] = (bf16_t)(m.y + softplus_f(r.y) * e.y);
    o[2] = (bf16_t)(m.z + softplus_f(r.z) * e.z);
    o[3] = (bf16_t)(m.w + softplus_f(r.w) * e.w);
    *(bf16x4_t*)(W + i) = o;
}

// ---- bias = b_mu + softplus(b_rho)*eps_b  (fp32) ----
__global__ __launch_bounds__(256) void biasgen_kernel(
    const float* __restrict__ mu, const float* __restrict__ rho,
    const float* __restrict__ eps, float* __restrict__ b)
{
    int i = blockIdx.x * 256 + threadIdx.x;
    b[i] = mu[i] + softplus_f(rho[i]) * eps[i];
}

// ---- LayerNorm per row of 4096, fp32 in -> bf16 out ----
__global__ __launch_bounds__(256) void ln_kernel(
    const float* __restrict__ x, const float* __restrict__ gamma,
    const float* __restrict__ beta, bf16_t* __restrict__ h)
{
    int row = blockIdx.x;
    const float* xr = x + (size_t)row * HDIM;
    int t = threadIdx.x;
    float4 v[4];
    float s = 0.f, s2 = 0.f;
#pragma unroll
    for (int j = 0; j < 4; ++j) {
        v[j] = *(const float4*)(xr + j * 1024 + t * 4);
        s  += v[j].x + v[j].y + v[j].z + v[j].w;
        s2 += v[j].x * v[j].x + v[j].y * v[j].y + v[j].z * v[j].z + v[j].w * v[j].w;
    }
#pragma unroll
    for (int off = 32; off > 0; off >>= 1) {
        s  += __shfl_down(s, off);
        s2 += __shfl_down(s2, off);
    }
    __shared__ float ps[4], ps2[4];
    if ((t & 63) == 0) { ps[t >> 6] = s; ps2[t >> 6] = s2; }
    __syncthreads();
    float tot  = ps[0] + ps[1] + ps[2] + ps[3];
    float tot2 = ps2[0] + ps2[1] + ps2[2] + ps2[3];
    float mean = tot * (1.f / HDIM);
    float var  = tot2 * (1.f / HDIM) - mean * mean;
    float rstd = rsqrtf(var + LN_EPS);
    bf16_t* hr = h + (size_t)row * HDIM;
#pragma unroll
    for (int j = 0; j < 4; ++j) {
        int c = j * 1024 + t * 4;
        float4 g  = *(const float4*)(gamma + c);
        float4 bb = *(const float4*)(beta + c);
        bf16x4_t o;
        o[0] = (bf16_t)((v[j].x - mean) * rstd * g.x + bb.x);
        o[1] = (bf16_t)((v[j].y - mean) * rstd * g.y + bb.y);
        o[2] = (bf16_t)((v[j].z - mean) * rstd * g.z + bb.z);
        o[3] = (bf16_t)((v[j].w - mean) * rstd * g.w + bb.w);
        *(bf16x4_t*)(hr + c) = o;
    }
}

__device__ __forceinline__ void gload_lds16(const bf16_t* g, const char* l) {
    __builtin_amdgcn_global_load_lds((gvoid_t*)g, (lvoid_t*)l, 16, 0, 0);
}

__device__ __forceinline__ bf16x8_t ds_read_b128_raw(const char* p) {
    f32x4_t r;
    asm volatile("ds_read_b128 %0, %1" : "=v"(r) : "v"((lvoid_t*)p));
    return __builtin_bit_cast(bf16x8_t, r);
}

// ---- GEMM: out[m][o] = x[m][o] + gelu( sum_k h[m][k]*W[o][k] + bias[o] ) ----
// m201-faithful template: 256x256 tile, BK=64, 8 waves (2Mx4N), double-buffered
// LDS (2 x 64KB: A 32KB + B 32KB), 4 phases/K-tile, 16 MFMA/phase (one
// C-quadrant x k-step), per-phase {reads; stage; [vmcnt]; barrier; lgkm(0);
// setprio+MFMA; barrier}. Counted vmcnt(2) at p0 & p3 only (never 0 in loop).
//
// Swizzle (row stride 128B): P = L ^ (((L>>7)&7)<<4) — involution, confined
// within each 128B row.
//
// Staging map (r8 BUGFIX): dest D = slab + w*1024 + lane*16 (linear) =>
// row_local(D) = w*8 + (lane>>3)  — the source row MUST include the w*8 term.
// Source col = 16B-slot (lane&7) ^ (row_local&7) = (lane&7) ^ (lane>>3).
//
// Hazard ledger (per wave, 2 gloads/phase):
//  (kt,p0) reads need B-all + A-early(kt)  -> drained by (kt-1,p3) vmcnt(2)
//    (8 outstanding there = kt's 4 stage-pairs; keep 2 = A-late(kt)),
//    published to all waves by (kt-1,p3)'s entry barrier.
//  (kt,p1) reads need A-late(kt)           -> drained by (kt,p0) vmcnt(2),
//    published by (kt,p0)'s entry barrier.
//  WAR: stages during kt target buf[1-cur]; its last reads (kt-1,p3) are
//    lgkm(0)-drained before that phase's exit barrier; stages issue after.
__global__ __launch_bounds__(512, 2) void gemm_kernel(
    const bf16_t* __restrict__ A,   // [8192][4096] h (bf16)
    const bf16_t* __restrict__ B,   // [4096][4096] W (bf16, row=o col=k)
    const float* __restrict__ bias, // [4096]
    const float* __restrict__ xres, // [8192][4096] residual fp32
    float* __restrict__ out)        // [8192][4096]
{
    __shared__ char lds[131072];    // dbuf d at d*65536: A at +0, B at +32768

    const int tid  = threadIdx.x;
    const int lane = tid & 63, w = tid >> 6;
    const int g = lane >> 4, fr = lane & 15;
    const int wm = w >> 2, wn = w & 3;   // wave grid 2(M) x 4(N)

    // T1: bijective XCD swizzle (512 blocks, 512%8==0)
    int bid = blockIdx.x;
    int wg  = (bid & 7) * 64 + (bid >> 3);
    const int tileN = (wg & 15) * 256;
    const int tileM = (wg >> 4) * 256;

    // staging source (BUGFIX: row includes w*8)
    const int srow = w * 8 + (lane >> 3);
    const int scol = 8 * ((lane & 7) ^ (lane >> 3));
    const bf16_t* srcA = A + (size_t)(tileM + srow) * HDIM + scol;
    const bf16_t* srcB = B + (size_t)(tileN + srow) * HDIM + scol;

    // swizzled read offsets (k-step j=0); j=1 is ^0x40 (swz maps bits 4-6
    // from row bits 0-2; L(j1)=L(j0)|0x40 -> P(j1)=P(j0)^0x40)
    int aoff[8], boff[4];
#pragma unroll
    for (int m = 0; m < 8; ++m) {
        int L = (wm * 128 + m * 16 + fr) * 128 + g * 16;
        aoff[m] = L ^ (((L >> 7) & 7) << 4);
    }
#pragma unroll
    for (int n = 0; n < 4; ++n) {
        int L = (wn * 64 + n * 16 + fr) * 128 + g * 16;
        boff[n] = 32768 + (L ^ (((L >> 7) & 7) << 4));
    }

    f32x4_t acc[8][4] = {};
    const int NT = HDIM / 64;  // 64 K-tiles

    bf16x8_t af0, af1, af2, af3, bv0, bv1, bv2, bv3;

#define CL(AF, R)                                                               \
    acc[R][0] = __builtin_amdgcn_mfma_f32_16x16x32_bf16(AF, bv0, acc[R][0], 0, 0, 0); \
    acc[R][1] = __builtin_amdgcn_mfma_f32_16x16x32_bf16(AF, bv1, acc[R][1], 0, 0, 0); \
    acc[R][2] = __builtin_amdgcn_mfma_f32_16x16x32_bf16(AF, bv2, acc[R][2], 0, 0, 0); \
    acc[R][3] = __builtin_amdgcn_mfma_f32_16x16x32_bf16(AF, bv3, acc[R][3], 0, 0, 0);
#define SCHEDB __builtin_amdgcn_sched_barrier(0)
#define BARRIER do { __builtin_amdgcn_s_barrier(); SCHEDB; } while (0)
#define LGKM0 do { asm volatile("s_waitcnt lgkmcnt(0)" ::: "memory"); SCHEDB; } while (0)
#define VMCNT(n) do { asm volatile("s_waitcnt vmcnt(" #n ")" ::: "memory"); SCHEDB; } while (0)
#define MFMA_BLK(A0, A1, A2, A3, R0, R1, R2, R3)       \
    __builtin_amdgcn_s_setprio(1);                      \
    CL(A0, R0) CL(A1, R1) CL(A2, R2) CL(A3, R3)         \
    __builtin_amdgcn_s_setprio(0);                      \
    SCHEDB;

    // prologue: stage tile 0 fully into buf0; one-time full drain
    {
        char* s0 = &lds[0];
        gload_lds16(srcB,              s0 + 32768 + w * 1024);
        gload_lds16(srcB +  64 * HDIM, s0 + 32768 +  8192 + w * 1024);
        gload_lds16(srcB + 128 * HDIM, s0 + 32768 + 16384 + w * 1024);
        gload_lds16(srcB + 192 * HDIM, s0 + 32768 + 24576 + w * 1024);
        gload_lds16(srcA,              s0 + w * 1024);
        gload_lds16(srcA + 128 * HDIM, s0 + 16384 + w * 1024);
        gload_lds16(srcA +  64 * HDIM, s0 +  8192 + w * 1024);
        gload_lds16(srcA + 192 * HDIM, s0 + 24576 + w * 1024);
        asm volatile("s_waitcnt vmcnt(0)" ::: "memory");
        BARRIER;
    }

#pragma unroll 1
    for (int kt = 0; kt < NT; ++kt) {
        const char* buf = &lds[(kt & 1) * 65536];
        char* stg = &lds[((kt + 1) & 1) * 65536];
        const int sk = ((kt + 1) & (NT - 1)) * 64;  // tail wrap: staged, never read

        // ---- p0: af0-3@j0 + bv@j0; stage B[0:128) of kt+1; vmcnt(2) ----
        af0 = ds_read_b128_raw(buf + aoff[0]);
        af1 = ds_read_b128_raw(buf + aoff[1]);
        af2 = ds_read_b128_raw(buf + aoff[2]);
        af3 = ds_read_b128_raw(buf + aoff[3]);
        bv0 = ds_read_b128_raw(buf + boff[0]);
        bv1 = ds_read_b128_raw(buf + boff[1]);
        bv2 = ds_read_b128_raw(buf + boff[2]);
        bv3 = ds_read_b128_raw(buf + boff[3]);
        gload_lds16(srcB + sk,             stg + 32768 + w * 1024);
        gload_lds16(srcB + 64 * HDIM + sk, stg + 32768 + 8192 + w * 1024);
        SCHEDB;
        VMCNT(2);
        BARRIER;
        LGKM0;
        MFMA_BLK(af0, af1, af2, af3, 0, 1, 2, 3)
        BARRIER;

        // ---- p1: af4-7@j0; stage B[128:256) ----
        af0 = ds_read_b128_raw(buf + aoff[4]);
        af1 = ds_read_b128_raw(buf + aoff[5]);
        af2 = ds_read_b128_raw(buf + aoff[6]);
        af3 = ds_read_b128_raw(buf + aoff[7]);
        gload_lds16(srcB + 128 * HDIM + sk, stg + 32768 + 16384 + w * 1024);
        gload_lds16(srcB + 192 * HDIM + sk, stg + 32768 + 24576 + w * 1024);
        SCHEDB;
        BARRIER;
        LGKM0;
        MFMA_BLK(af0, af1, af2, af3, 4, 5, 6, 7)
        BARRIER;

        // ---- p2: af0-3@j1 + bv@j1; stage A[0:64)u[128:192) ----
        af0 = ds_read_b128_raw(buf + (aoff[0] ^ 64));
        af1 = ds_read_b128_raw(buf + (aoff[1] ^ 64));
        af2 = ds_read_b128_raw(buf + (aoff[2] ^ 64));
        af3 = ds_read_b128_raw(buf + (aoff[3] ^ 64));
        bv0 = ds_read_b128_raw(buf + (boff[0] ^ 64));
        bv1 = ds_read_b128_raw(buf + (boff[1] ^ 64));
        bv2 = ds_read_b128_raw(buf + (boff[2] ^ 64));
        bv3 = ds_read_b128_raw(buf + (boff[3] ^ 64));
        gload_lds16(srcA + sk,              stg + w * 1024);
        gload_lds16(srcA + 128 * HDIM + sk, stg + 16384 + w * 1024);
        SCHEDB;
        BARRIER;
        LGKM0;
        MFMA_BLK(af0, af1, af2, af3, 0, 1, 2, 3)
        BARRIER;

        // ---- p3: af4-7@j1; stage A[64:128)u[192:256); vmcnt(2) ----
        af0 = ds_read_b128_raw(buf + (aoff[4] ^ 64));
        af1 = ds_read_b128_raw(buf + (aoff[5] ^ 64));
        af2 = ds_read_b128_raw(buf + (aoff[6] ^ 64));
        af3 = ds_read_b128_raw(buf + (aoff[7] ^ 64));
        gload_lds16(srcA + 64 * HDIM + sk,  stg + 8192 + w * 1024);
        gload_lds16(srcA + 192 * HDIM + sk, stg + 24576 + w * 1024);
        SCHEDB;
        VMCNT(2);
        BARRIER;
        LGKM0;
        MFMA_BLK(af0, af1, af2, af3, 4, 5, 6, 7)
        BARRIER;
    }
#undef MFMA_BLK
#undef CL

    // epilogue: bias + exact GELU + residual, fp32 out
    // C/D layout: col = lane&15, row = (lane>>4)*4 + j
    const int col0 = tileN + wn * 64 + fr;
    const int row0 = tileM + wm * 128 + g * 4;
#pragma unroll
    for (int n = 0; n < 4; ++n) {
        float bvv = bias[col0 + n * 16];
#pragma unroll
        for (int m = 0; m < 8; ++m) {
#pragma unroll
            for (int j = 0; j < 4; ++j) {
                size_t idx = (size_t)(row0 + m * 16 + j) * HDIM + (col0 + n * 16);
                float v = acc[m][n][j] + bvv;
                float ge = 0.5f * v * (1.0f + erff(v * 0.70710678118654752f));
                out[idx] = xres[idx] + ge;
            }
        }
    }
}

extern "C" void kernel_launch(void* const* d_in, const int* in_sizes, int n_in,
                              void* d_out, int out_size, void* d_ws, size_t ws_size,
                              hipStream_t stream) {
    const float* x        = (const float*)d_in[0];
    const float* ln_gamma = (const float*)d_in[1];
    const float* ln_beta  = (const float*)d_in[2];
    const float* w_mu     = (const float*)d_in[3];
    const float* w_rho    = (const float*)d_in[4];
    const float* b_mu     = (const float*)d_in[5];
    const float* b_rho    = (const float*)d_in[6];
    const float* eps_w    = (const float*)d_in[7];
    const float* eps_b    = (const float*)d_in[8];
    float* out = (float*)d_out;

    char* ws = (char*)d_ws;
    bf16_t* h_bf16 = (bf16_t*)ws;                              // 64 MiB
    bf16_t* W_bf16 = (bf16_t*)(ws + 67108864);                 // 32 MiB
    float*  bias   = (float*)(ws + 67108864 + 33554432);       // 16 KiB

    wgen_kernel<<<16384, 256, 0, stream>>>(w_mu, w_rho, eps_w, W_bf16);
    biasgen_kernel<<<16, 256, 0, stream>>>(b_mu, b_rho, eps_b, bias);
    ln_kernel<<<MROWS, 256, 0, stream>>>(x, ln_gamma, ln_beta, h_bf16);
    gemm_kernel<<<512, 512, 0, stream>>>(h_bf16, W_bf16, bias, x, out);
}